// Round 4
// baseline (269.916 us; speedup 1.0000x reference)
//
#include <hip/hip_runtime.h>

// BoundaryKDV7: per-pixel channel-softmax KL(T||S), masked by class-boundary
// pixels, binned per (batch, class 1..13), normalized, summed to scalar.
//
// Shapes: preds_S/preds_T [8,14,512,512] f32, gt [8,1,512,512] i32, out: 1 f32.
//
// R3: global->LDS async DMA staging. R0-R2 post-mortem: all register-path
// variants plateau at 2.4-2.6 TB/s because the compiler serializes the 28
// strided loads (VGPR_Count 20-68, ~6 KB/CU in flight). global_load_lds
// width=16 makes MLP explicit (7 x 1KB outstanding per wave, no VGPR cost):
// tile = 256 px so one channel slice == one 1 KB DMA instruction.

#define CC 14
#define KB 13          // boundary classes 1..13
#define BB 8
#define HH 512
#define WW 512
#define PP (HH * WW)   // 262144 pixels per image
#define TILE 256
#define TILES_PER_IMG (PP / TILE)   // 1024
#define CHUNKS (2 * CC)             // 28 x 1KB DMA chunks (14 S + 14 T)

// ws layout (floats): [0 .. 103] kl_sum[b][k-1], [104 .. 207] n[b][k-1]
#define NBINS (BB * KB)

__global__ void zero_ws_kernel(float* __restrict__ ws) {
    int i = threadIdx.x;
    if (i < 2 * NBINS) ws[i] = 0.0f;
}

__global__ __launch_bounds__(256) void boundary_kl_kernel(
        const float* __restrict__ S, const float* __restrict__ T,
        const int* __restrict__ gt, float* __restrict__ ws) {
    const int tid  = threadIdx.x;
    const int wid  = tid >> 6;
    const int lane = tid & 63;
    const int b    = blockIdx.x / TILES_PER_IMG;
    const int p0   = (blockIdx.x % TILES_PER_IMG) * TILE;

    __shared__ float lds[CHUNKS * TILE];   // 28 KB: S ch c at c*TILE, T at (14+c)*TILE
    __shared__ float s_kl[KB + 1];
    __shared__ float s_n[KB + 1];
    if (tid <= KB) { s_kl[tid] = 0.0f; s_n[tid] = 0.0f; }

    const float* Sb = S + (size_t)b * CC * PP + p0;
    const float* Tb = T + (size_t)b * CC * PP + p0;
    const int*  gtb = gt + (size_t)b * PP;

    // ---- issue 7 async 1KB global->LDS DMAs per wave (no VGPR cost) ----
#pragma unroll
    for (int i = 0; i < 7; ++i) {
        const int j  = wid * 7 + i;                 // 0..27, wave-uniform
        const int ch = (j < CC) ? j : j - CC;
        const float* gsrc = ((j < CC) ? Sb : Tb) + (size_t)ch * PP + lane * 4;
        __builtin_amdgcn_global_load_lds(
            (const __attribute__((address_space(1))) void*)gsrc,
            (__attribute__((address_space(3))) void*)&lds[j * TILE],
            16, 0, 0);
    }

    // ---- gt boundary test for this thread's pixel (overlaps the DMA) ----
    const int p = p0 + tid;
    const int k = gtb[p];
    const int h = p >> 9;
    const int w = p & (WW - 1);
    const int gu = (h > 0)      ? gtb[p - WW] : -1;
    const int gd = (h < HH - 1) ? gtb[p + WW] : -1;
    const int gl = (w > 0)      ? gtb[p - 1]  : -1;
    const int gr = (w < WW - 1) ? gtb[p + 1]  : -1;
    const bool eroded = (gu == k) & (gd == k) & (gl == k) & (gr == k);
    const bool contrib = (k >= 1) && !eroded;

    __syncthreads();   // drains vmcnt(0): all 28 chunks landed in LDS

    // ---- per-pixel log-softmax KL from LDS (stride-1: 2 lanes/bank, free) ----
    float xs[CC], xt[CC];
#pragma unroll
    for (int c = 0; c < CC; ++c) {
        xs[c] = lds[c * TILE + tid];
        xt[c] = lds[(CC + c) * TILE + tid];
    }

    float mS = xs[0], mT = xt[0];
#pragma unroll
    for (int c = 1; c < CC; ++c) { mS = fmaxf(mS, xs[c]); mT = fmaxf(mT, xt[c]); }

    float zS = 0.f, zT = 0.f, A = 0.f;
#pragma unroll
    for (int c = 0; c < CC; ++c) {
        float eS = __expf(xs[c] - mS);
        float eT = __expf(xt[c] - mT);
        zS += eS;
        zT += eT;
        A  += eT * (xt[c] - xs[c]);
    }
    // kl = A/ZT + (mS + log ZS) - (mT + log ZT)
    const float kl = A / zT + (mS + __logf(zS)) - (mT + __logf(zT));

    if (contrib) {
        atomicAdd(&s_kl[k], kl);
        atomicAdd(&s_n[k], 1.0f);
    }
    __syncthreads();

    if (tid >= 1 && tid <= KB) {
        atomicAdd(&ws[b * KB + (tid - 1)], s_kl[tid]);
        atomicAdd(&ws[NBINS + b * KB + (tid - 1)], s_n[tid]);
    }
}

__global__ void finalize_kernel(const float* __restrict__ ws,
                                const int* __restrict__ gt,
                                float* __restrict__ out) {
    __shared__ float partial[128];
    const int tid = threadIdx.x;  // 128 threads
    float t = 0.0f;
    if (tid < NBINS) {
        const int b = tid / KB;
        const int k = (tid % KB) + 1;
        const float kl = ws[tid];
        const float n  = ws[NBINS + tid];
        // Pixel p=0 of image b is a corner -> boundary iff gt[b,0,0] >= 1.
        // valid = exists boundary pixel with flat index > 0.
        const int k0 = gt[(size_t)b * PP];
        const float sub = (k0 == k) ? 1.0f : 0.0f;   // k >= 1 always here
        const float npos = n - sub;
        t = (npos > 0.0f) ? (kl / ((float)CC * fmaxf(n, 1.0f))) : 0.0f;
    }
    partial[tid] = t;
    __syncthreads();
    for (int s = 64; s > 0; s >>= 1) {
        if (tid < s) partial[tid] += partial[tid + s];
        __syncthreads();
    }
    if (tid == 0) out[0] = partial[0];  // LOSS_WEIGHT * TAU^2 = 1
}

extern "C" void kernel_launch(void* const* d_in, const int* in_sizes, int n_in,
                              void* d_out, int out_size, void* d_ws, size_t ws_size,
                              hipStream_t stream) {
    const float* S  = (const float*)d_in[0];
    const float* T  = (const float*)d_in[1];
    const int*   gt = (const int*)d_in[2];
    float* out = (float*)d_out;
    float* ws  = (float*)d_ws;

    hipLaunchKernelGGL(zero_ws_kernel, dim3(1), dim3(256), 0, stream, ws);
    hipLaunchKernelGGL(boundary_kl_kernel, dim3(BB * TILES_PER_IMG), dim3(256), 0, stream,
                       S, T, gt, ws);
    hipLaunchKernelGGL(finalize_kernel, dim3(1), dim3(128), 0, stream, ws, gt, out);
}

// Round 5
// 257.013 us; speedup vs baseline: 1.0502x; 1.0502x over previous
//
#include <hip/hip_runtime.h>

// BoundaryKDV7: per-pixel channel-softmax KL(T||S), masked by class-boundary
// pixels, binned per (batch, class 1..13), normalized, summed to scalar.
//
// Shapes: preds_S/preds_T [8,14,512,512] f32, gt [8,1,512,512] i32, out: 1 f32.
//
// R4: per-wave autonomous DMA pipeline. R0-R3 post-mortem: every structure
// plateaued at 2.3-2.6 TB/s because requests were burst-then-drain (in-flight
// duty cycle ~12%, ~2.5 MB chip-wide avg -> Little's law caps BW). Here each
// wave owns a 7 KB LDS strip and loops 4 tiles of 64 px: issue 28 x 256 B
// global_load_lds + gt loads, wave-local s_waitcnt vmcnt(0) (NO block
// barrier), compute, repeat. 20 waves/CU x 7 KB x ~0.8 duty ~= 29 MB in
// flight chip-wide.

#define CC 14
#define KB 13          // boundary classes 1..13
#define BB 8
#define HH 512
#define WW 512
#define PP (HH * WW)   // 262144 pixels per image
#define TPW 4                       // tiles per wave
#define TILE 64                     // px per tile (one wave-load)
#define PX_PER_BLOCK (4 * TPW * TILE)        // 1024
#define BLOCKS_PER_IMG (PP / PX_PER_BLOCK)   // 256
#define WSTRIP (2 * CC * TILE)      // floats per wave strip (1792 = 7 KB)

// ws layout (floats): [0 .. 103] kl_sum[b][k-1], [104 .. 207] n[b][k-1]
#define NBINS (BB * KB)

__global__ void zero_ws_kernel(float* __restrict__ ws) {
    int i = threadIdx.x;
    if (i < 2 * NBINS) ws[i] = 0.0f;
}

__global__ __launch_bounds__(256) void boundary_kl_kernel(
        const float* __restrict__ S, const float* __restrict__ T,
        const int* __restrict__ gt, float* __restrict__ ws) {
    const int tid  = threadIdx.x;
    const int wid  = tid >> 6;
    const int lane = tid & 63;
    const int b    = blockIdx.x / BLOCKS_PER_IMG;
    const int pblk = (blockIdx.x % BLOCKS_PER_IMG) * PX_PER_BLOCK;

    __shared__ float lds[4 * WSTRIP];   // 28 KB, 7 KB per wave
    __shared__ float s_kl[KB + 1];
    __shared__ float s_n[KB + 1];
    if (tid <= KB) { s_kl[tid] = 0.0f; s_n[tid] = 0.0f; }
    __syncthreads();   // bins ready before any wave's atomics

    float* wbuf = &lds[wid * WSTRIP];
    const float* Sb = S + (size_t)b * CC * PP;
    const float* Tb = T + (size_t)b * CC * PP;
    const int*  gtb = gt + (size_t)b * PP;

    for (int t = 0; t < TPW; ++t) {
        const int p0 = pblk + wid * (TPW * TILE) + t * TILE;

        // ---- issue 28 x 256 B async global->LDS DMAs (wave-uniform dest) ----
#pragma unroll
        for (int c = 0; c < CC; ++c) {
            __builtin_amdgcn_global_load_lds(
                (const __attribute__((address_space(1))) void*)(Sb + (size_t)c * PP + p0 + lane),
                (__attribute__((address_space(3))) void*)&wbuf[c * TILE],
                4, 0, 0);
        }
#pragma unroll
        for (int c = 0; c < CC; ++c) {
            __builtin_amdgcn_global_load_lds(
                (const __attribute__((address_space(1))) void*)(Tb + (size_t)c * PP + p0 + lane),
                (__attribute__((address_space(3))) void*)&wbuf[(CC + c) * TILE],
                4, 0, 0);
        }

        // ---- gt boundary test for this lane's pixel (overlaps DMA flight) ----
        const int p = p0 + lane;
        const int k = gtb[p];
        const int h = p >> 9;
        const int w = p & (WW - 1);
        const int gu = (h > 0)      ? gtb[p - WW] : -1;
        const int gd = (h < HH - 1) ? gtb[p + WW] : -1;
        const int gl = (w > 0)      ? gtb[p - 1]  : -1;
        const int gr = (w < WW - 1) ? gtb[p + 1]  : -1;
        const bool eroded = (gu == k) & (gd == k) & (gl == k) & (gr == k);
        const bool contrib = (k >= 1) && !eroded;

        // ---- wave-local drain: vmcnt(0), lgkmcnt/expcnt = no-wait ----
        __builtin_amdgcn_s_waitcnt(0x0F70);
        __builtin_amdgcn_sched_barrier(0);   // no ds_read hoisted above the wait

        // ---- per-pixel log-softmax KL from this wave's LDS strip ----
        float xs[CC], xt[CC];
#pragma unroll
        for (int c = 0; c < CC; ++c) {
            xs[c] = wbuf[c * TILE + lane];
            xt[c] = wbuf[(CC + c) * TILE + lane];
        }

        float mS = xs[0], mT = xt[0];
#pragma unroll
        for (int c = 1; c < CC; ++c) { mS = fmaxf(mS, xs[c]); mT = fmaxf(mT, xt[c]); }

        float zS = 0.f, zT = 0.f, A = 0.f;
#pragma unroll
        for (int c = 0; c < CC; ++c) {
            float eS = __expf(xs[c] - mS);
            float eT = __expf(xt[c] - mT);
            zS += eS;
            zT += eT;
            A  += eT * (xt[c] - xs[c]);
        }
        // kl = A/ZT + (mS + log ZS) - (mT + log ZT)
        const float kl = A / zT + (mS + __logf(zS)) - (mT + __logf(zT));

        if (contrib) {
            atomicAdd(&s_kl[k], kl);
            atomicAdd(&s_n[k], 1.0f);
        }
    }

    __syncthreads();   // all waves' bin updates done
    if (tid >= 1 && tid <= KB) {
        atomicAdd(&ws[b * KB + (tid - 1)], s_kl[tid]);
        atomicAdd(&ws[NBINS + b * KB + (tid - 1)], s_n[tid]);
    }
}

__global__ void finalize_kernel(const float* __restrict__ ws,
                                const int* __restrict__ gt,
                                float* __restrict__ out) {
    __shared__ float partial[128];
    const int tid = threadIdx.x;  // 128 threads
    float t = 0.0f;
    if (tid < NBINS) {
        const int b = tid / KB;
        const int k = (tid % KB) + 1;
        const float kl = ws[tid];
        const float n  = ws[NBINS + tid];
        // Pixel p=0 of image b is a corner -> boundary iff gt[b,0,0] >= 1.
        // valid = exists boundary pixel with flat index > 0.
        const int k0 = gt[(size_t)b * PP];
        const float sub = (k0 == k) ? 1.0f : 0.0f;   // k >= 1 always here
        const float npos = n - sub;
        t = (npos > 0.0f) ? (kl / ((float)CC * fmaxf(n, 1.0f))) : 0.0f;
    }
    partial[tid] = t;
    __syncthreads();
    for (int s = 64; s > 0; s >>= 1) {
        if (tid < s) partial[tid] += partial[tid + s];
        __syncthreads();
    }
    if (tid == 0) out[0] = partial[0];  // LOSS_WEIGHT * TAU^2 = 1
}

extern "C" void kernel_launch(void* const* d_in, const int* in_sizes, int n_in,
                              void* d_out, int out_size, void* d_ws, size_t ws_size,
                              hipStream_t stream) {
    const float* S  = (const float*)d_in[0];
    const float* T  = (const float*)d_in[1];
    const int*   gt = (const int*)d_in[2];
    float* out = (float*)d_out;
    float* ws  = (float*)d_ws;

    hipLaunchKernelGGL(zero_ws_kernel, dim3(1), dim3(256), 0, stream, ws);
    hipLaunchKernelGGL(boundary_kl_kernel, dim3(BB * BLOCKS_PER_IMG), dim3(256), 0, stream,
                       S, T, gt, ws);
    hipLaunchKernelGGL(finalize_kernel, dim3(1), dim3(128), 0, stream, ws, gt, out);
}